// Round 19
// baseline (126.555 us; speedup 1.0000x reference)
//
#include <hip/hip_runtime.h>

typedef _Float16 f16;
typedef _Float16 f16x8 __attribute__((ext_vector_type(8)));
typedef _Float16 f16x4 __attribute__((ext_vector_type(4)));
typedef float    f32x4 __attribute__((ext_vector_type(4)));
typedef unsigned int u32;
typedef unsigned int u32x4 __attribute__((ext_vector_type(4)));

#define LOG2E 1.44269504088896340736f
#define EXPC  (13.0f * 1.44269504088896340736f)   // fixed softmax shift (log2 units)

__device__ __forceinline__ void gload_lds16(const void* g, void* l) {
  __builtin_amdgcn_global_load_lds(
      (const __attribute__((address_space(1))) void*)g,
      (__attribute__((address_space(3))) void*)l, 16, 0, 0);
}

__device__ __forceinline__ void block_sync() {
  asm volatile("" ::: "memory");
  __builtin_amdgcn_s_barrier();
  asm volatile("" ::: "memory");
}

// ---------------- fused prep: cast_x (blocks 0..4095) + w_attn^T (4096..7167)
// + w_proj^T (7168..8191), one launch ----------------
__global__ __launch_bounds__(256)
void k_prep(const float* __restrict__ x, f16* __restrict__ xh,
            const float* __restrict__ w_attn, f16* __restrict__ waT,
            const float* __restrict__ w_proj, f16* __restrict__ wpT) {
  __shared__ float tile[32][33];
  const int bid = blockIdx.x;
  const int t = threadIdx.x;
  if (bid < 4096) {
    int i = bid * 256 + t;
    f32x4 v = ((const f32x4*)x)[i];
    f16x4 o;
    o[0] = (f16)v[0]; o[1] = (f16)v[1]; o[2] = (f16)v[2]; o[3] = (f16)v[3];
    ((f16x4*)xh)[i] = o;
    return;
  }
  const float* in; f16* out; int R, C, bx, by;
  if (bid < 4096 + 3072) {
    int q = bid - 4096; in = w_attn; out = waT; R = 1024; C = 3072;
    bx = q % 96; by = q / 96;
  } else {
    int q = bid - 7168; in = w_proj; out = wpT; R = 1024; C = 1024;
    bx = q % 32; by = q / 32;
  }
  int tx = t & 31, ty = t >> 5;   // (32,8)
  int c0 = bx * 32, r0 = by * 32;
#pragma unroll
  for (int i = 0; i < 4; i++)
    tile[ty + i * 8][tx] = in[(size_t)(r0 + ty + i * 8) * C + c0 + tx];
  __syncthreads();
#pragma unroll
  for (int i = 0; i < 4; i++)
    out[(size_t)(c0 + ty + i * 8) * R + r0 + tx] = (f16)tile[tx][ty + i * 8];
}

// ---------------- GEMM: A[M,1024] fp16 @ BT[N,1024] fp16 ----------------
// 2-phase prefetch, double-buffered 64KB LDS, T2 XOR bank-swizzle (R10-proven).
// EPI 0: n<1024 -> Q into qk (scaled by LOG2E);
//        1024<=n<2048 -> K in FRAGMENT-NATIVE layout kb[bh][S][cc][hf][lane][8]
//          (one MFMA A-frag = contiguous 1KB; attn reads it barrier/LDS-free);
//        n>=2048 -> V blocked vT2[bh][kv/8][d:64][j:8].
// EPI 1: float out + b_proj.
template <int EPI>
__global__ __launch_bounds__(256)
void k_gemm(const f16* __restrict__ A, const f16* __restrict__ BT,
            const float* __restrict__ bias,
            f16* __restrict__ out_qk, f16* __restrict__ out_kb,
            f16* __restrict__ out_vT, float* __restrict__ out_f) {
  constexpr int K = 1024;
  __shared__ f16 smem[4][128 * 64];
  const int t = threadIdx.x;
  const int l = t & 63;
  const int w = t >> 6;
  const int wm = (w >> 1) * 64;
  const int wn = (w & 1) * 64;
  const int m0 = blockIdx.x * 128;
  const int n0 = blockIdx.y * 128;
  const int lr = l & 15;
  const int lg = l >> 4;
  const int fr8 = lr & 7;

  const int row8g = t >> 3;
  const int scg = (t & 7) ^ (row8g & 7);
  const f16* Ap = A + (size_t)(m0 + row8g) * K + scg * 8;
  const f16* Bp = BT + (size_t)(n0 + row8g) * K + scg * 8;

#define GSTAGE(buf) do { \
    _Pragma("unroll") \
    for (int i2 = 0; i2 < 4; i2++) \
      gload_lds16(Ap + (size_t)(i2 * 32) * K, &smem[buf][(i2 * 256 + t) * 8]); \
    _Pragma("unroll") \
    for (int i2 = 0; i2 < 4; i2++) \
      gload_lds16(Bp + (size_t)(i2 * 32) * K, &smem[2 + buf][(i2 * 256 + t) * 8]); \
    Ap += 64; Bp += 64; } while (0)

  f32x4 acc[4][4] = {};

#define GCOMPUTE(buf) do { \
    _Pragma("unroll") \
    for (int kk = 0; kk < 64; kk += 32) { \
      const int cbase = (kk >> 3) + lg; \
      f16x8 af[4], bf[4]; \
      _Pragma("unroll") \
      for (int i = 0; i < 4; i++) \
        af[i] = *(const f16x8*)&smem[buf][((wm + i * 16 + lr) * 8 + (cbase ^ fr8)) * 8]; \
      _Pragma("unroll") \
      for (int j = 0; j < 4; j++) \
        bf[j] = *(const f16x8*)&smem[2 + buf][((wn + j * 16 + lr) * 8 + (cbase ^ fr8)) * 8]; \
      _Pragma("unroll") \
      for (int i = 0; i < 4; i++) \
        _Pragma("unroll") \
        for (int j = 0; j < 4; j++) \
          acc[i][j] = __builtin_amdgcn_mfma_f32_16x16x32_f16(af[i], bf[j], acc[i][j], 0, 0, 0); \
    } } while (0)

  GSTAGE(0);
  asm volatile("s_waitcnt vmcnt(0)" ::: "memory");
  block_sync();

  for (int kt = 0; kt < 16; kt += 2) {
    GSTAGE(1);
    GCOMPUTE(0);
    asm volatile("s_waitcnt vmcnt(0)" ::: "memory");
    block_sync();
    if (kt + 2 < 16) GSTAGE(0);
    GCOMPUTE(1);
    asm volatile("s_waitcnt vmcnt(0)" ::: "memory");
    block_sync();
  }
#undef GSTAGE
#undef GCOMPUTE

  if (EPI == 1) {
#pragma unroll
    for (int i = 0; i < 4; i++) {
      int mbase = m0 + wm + i * 16 + (l >> 4) * 4;
#pragma unroll
      for (int j = 0; j < 4; j++) {
        int n = n0 + wn + j * 16 + lr;
        float bv = bias[n];
#pragma unroll
        for (int r = 0; r < 4; r++)
          out_f[(size_t)(mbase + r) * 1024 + n] = acc[i][j][r] + bv;
      }
    }
  } else if (n0 < 1024) {
    // Q: row-coalesced, scaled by LOG2E
#pragma unroll
    for (int i = 0; i < 4; i++) {
      int mbase = m0 + wm + i * 16 + (l >> 4) * 4;
#pragma unroll
      for (int j = 0; j < 4; j++) {
        int n = n0 + wn + j * 16 + lr;
        float bv = bias[n];
#pragma unroll
        for (int r = 0; r < 4; r++)
          out_qk[(size_t)(mbase + r) * 2048 + n] = (f16)((acc[i][j][r] + bv) * LOG2E);
      }
    }
  } else {
    // K and V: transpose via XOR-swizzled LDS scratch, then layout-specific writes
    f16* scr = &smem[0][0];   // logical [nl:128][s:128]; elem s at s ^ ((nl&15)<<3)
#pragma unroll
    for (int i = 0; i < 4; i++) {
      int s0 = wm + i * 16 + (l >> 4) * 4;
#pragma unroll
      for (int j = 0; j < 4; j++) {
        int nl = wn + j * 16 + lr;
        float bv = bias[n0 + nl];
        f16x4 pv;
#pragma unroll
        for (int r = 0; r < 4; r++) pv[r] = (f16)(acc[i][j][r] + bv);
        *(f16x4*)&scr[nl * 128 + (s0 ^ ((nl & 15) << 3))] = pv;
      }
    }
    block_sync();
    const int b = m0 >> 11;
    if (n0 < 2048) {
      // K -> fragment-native kb. Frag (bh, S=kv>>5, cc, hf): lane lp holds
      // K[kv = S*32 + 2*(lp&15) + cc][d = (hf*4 + (lp>>4))*8 + j], j=0..7.
      const int Sg0 = (m0 & 2047) >> 5;   // 4 S-groups in this tile
      const int h0 = (n0 - 1024) >> 6;    // 2 heads in this tile
      const int kbi = t >> 3;             // 0..31: (bh_l,S_l,cc,hf)
      const int li = t & 7;
      const int hf   = kbi & 1;
      const int cc   = (kbi >> 1) & 1;
      const int S_l  = (kbi >> 2) & 3;
      const int bh_l = kbi >> 4;
      size_t kbidx = ((((size_t)(b * 16 + h0 + bh_l) * 64 + Sg0 + S_l) * 2 + cc) * 2 + hf);
      f16* dst = out_kb + kbidx * 512;
#pragma unroll
      for (int e = 0; e < 8; e++) {
        int lp = li * 8 + e;
        int s = S_l * 32 + 2 * (lp & 15) + cc;
        int nlb = bh_l * 64 + (hf * 4 + (lp >> 4)) * 8;
        f16x8 vv;
#pragma unroll
        for (int j = 0; j < 8; j++) {
          int nl = nlb + j;
          vv[j] = scr[nl * 128 + (s ^ ((nl & 15) << 3))];
        }
        *(f16x8*)&dst[lp * 8] = vv;
      }
    } else {
      // V -> blocked vT2[bh][kv/8][d:64][j:8]
      const int kvc0 = (m0 & 2047) >> 3;
      const int h0 = (n0 - 2048) >> 6;
      const int l64 = t & 63;
      const int wv = t >> 6;
#pragma unroll
      for (int p = 0; p < 8; p++) {
        int pair = wv + p * 4;
        int kvcl = pair & 15;
        int hgl  = pair >> 4;
        int nl = hgl * 64 + l64;
        f16x8 vv = *(const f16x8*)&scr[nl * 128 + ((kvcl * 8) ^ ((nl & 15) << 3))];
        size_t dst = (((size_t)(b * 16 + h0 + hgl) * 256 + kvc0 + kvcl) * 64 + l64) * 8;
        *(f16x8*)&out_vT[dst] = vv;
      }
    }
  }
}

// ---------------- flash attention: BARRIER-FREE, LDS-FREE ----------------
// grid 1024 (XCD-swizzled), 4-wave blocks, 16 q-rows/wave. K AND V read directly
// from L2 in fragment-native layouts (kb: 1KB/frag contiguous; vT2 blocked) --
// every load is 16B/lane coalesced. NO LDS, NO barriers, NO vmcnt asm: each wave
// free-runs; 16 waves/CU skew naturally (the per-tile barrier+drain cadence was
// the residual cost after R17 zeroed conflicts). Per-XCD K+V ~2MB = L2-resident.
// kv/d semantics identical to R17 (kv = S*32 + 2*lr + cc interleave).
// Swapped mfma(K,Q); Q pre-scaled LOG2E; QK C-init -EXPC; raw v_exp_f32;
// ones-MFMA row sums.
__global__ __launch_bounds__(256, 4)
void k_attn(const f16* __restrict__ qk, const f16* __restrict__ kb,
            const f16* __restrict__ vT, f16* __restrict__ aout) {
  const int t = threadIdx.x;
  const int l = t & 63;
  const int w = t >> 6;
  const int lr = l & 15;
  const int lg = l >> 4;
  const int lk = lg * 8;

  const int o  = (blockIdx.x & 7) * 128 + (blockIdx.x >> 3);  // XCD swizzle
  const int qt = o & 31;
  const int bh = o >> 5;
  const int b  = bh >> 4;
  const int h  = bh & 15;
  const int q0 = qt * 64 + w * 16;

  const f16* qp = qk + (size_t)(b * 2048 + q0 + lr) * 2048 + h * 64 + lk;
  f16x8 qf0 = *(const f16x8*)qp;
  f16x8 qf1 = *(const f16x8*)(qp + 32);

  // K fragment base: per bh = 64 S x 2 cc x 2 hf x 512 f16 = 131072 f16.
  // Frag (tt,ks,cc,hf) at (8*tt + 4*ks + 2*cc + hf)*512 + l*8.
  const f16* kbp = kb + (size_t)bh * 131072 + l * 8;
  // V direct (blocked vT2): lane (lr,lg) reads d-row, chunk = tile*8 + ks*4 + lg
  const f16* vg0 = vT + (((size_t)bh * 256 + lg) * 64 + lr) * 8;

  f32x4 oa[4] = {};
  f32x4 ssum = {};
  const f32x4 initc = {-EXPC, -EXPC, -EXPC, -EXPC};
  f16x8 ones;
#pragma unroll
  for (int j = 0; j < 8; j++) ones[j] = (f16)1.0f;

  for (int tt = 0; tt < 32; tt++) {
    // V frags (consumed by PV at end -> L2 latency hidden under QK+exp)
    f16x8 vfr[4][2];
#pragma unroll
    for (int c4 = 0; c4 < 4; c4++)
#pragma unroll
      for (int ks = 0; ks < 2; ks++)
        vfr[c4][ks] = *(const f16x8*)(vg0 + ks * 2048 + c4 * 128);

    f32x4 sa[4];
    __builtin_amdgcn_s_setprio(1);
#pragma unroll
    for (int c = 0; c < 4; c++) {
      const int ks = c >> 1, cc = c & 1;
      f16x8 kf0 = *(const f16x8*)(kbp + (4 * ks + 2 * cc + 0) * 512);
      f16x8 kf1 = *(const f16x8*)(kbp + (4 * ks + 2 * cc + 1) * 512);
      sa[c] = __builtin_amdgcn_mfma_f32_16x16x32_f16(kf0, qf0, initc, 0, 0, 0);
      sa[c] = __builtin_amdgcn_mfma_f32_16x16x32_f16(kf1, qf1, sa[c], 0, 0, 0);
    }
    __builtin_amdgcn_s_setprio(0);
#pragma unroll
    for (int c = 0; c < 4; c++)
#pragma unroll
      for (int r = 0; r < 4; r++)
        sa[c][r] = __builtin_amdgcn_exp2f(sa[c][r]);
    u32 pka[2][4];
#pragma unroll
    for (int ks = 0; ks < 2; ks++)
#pragma unroll
      for (int u = 0; u < 4; u++)
        pka[ks][u] = __builtin_bit_cast(u32,
            __builtin_amdgcn_cvt_pkrtz(sa[2 * ks][u], sa[2 * ks + 1][u]));
    f16x8 pa0 = __builtin_bit_cast(f16x8, (u32x4){pka[0][0], pka[0][1], pka[0][2], pka[0][3]});
    f16x8 pa1 = __builtin_bit_cast(f16x8, (u32x4){pka[1][0], pka[1][1], pka[1][2], pka[1][3]});
    __builtin_amdgcn_s_setprio(1);
    ssum = __builtin_amdgcn_mfma_f32_16x16x32_f16(pa0, ones, ssum, 0, 0, 0);
    ssum = __builtin_amdgcn_mfma_f32_16x16x32_f16(pa1, ones, ssum, 0, 0, 0);
#pragma unroll
    for (int c4 = 0; c4 < 4; c4++) {
      oa[c4] = __builtin_amdgcn_mfma_f32_16x16x32_f16(pa0, vfr[c4][0], oa[c4], 0, 0, 0);
      oa[c4] = __builtin_amdgcn_mfma_f32_16x16x32_f16(pa1, vfr[c4][1], oa[c4], 0, 0, 0);
    }
    __builtin_amdgcn_s_setprio(0);

    kbp += 4096;   // 8 frags x 512 f16 per tile
    vg0 += 4096;   // 8 kv-chunks x 512 f16 per tile
  }

  // ---- final: normalize (ssum[r] = row-sum for q = q0 + lg*4 + r) ----
#pragma unroll
  for (int r = 0; r < 4; r++) {
    float ia = 1.0f / ssum[r];
    size_t rowa = (size_t)(b * 2048 + q0 + lg * 4 + r);
#pragma unroll
    for (int c4 = 0; c4 < 4; c4++)
      aout[rowa * 1024 + h * 64 + c4 * 16 + lr] = (f16)(oa[c4][r] * ia);
  }
}

// ---------------- launch ----------------
extern "C" void kernel_launch(void* const* d_in, const int* in_sizes, int n_in,
                              void* d_out, int out_size, void* d_ws, size_t ws_size,
                              hipStream_t stream) {
  const float* x      = (const float*)d_in[0];
  const float* w_attn = (const float*)d_in[1];
  const float* b_attn = (const float*)d_in[2];
  const float* w_proj = (const float*)d_in[3];
  const float* b_proj = (const float*)d_in[4];
  float* out = (float*)d_out;

  char* p = (char*)d_ws;
  f16* xh  = (f16*)p;  p += (size_t)4096 * 1024 * 2;
  f16* waT = (f16*)p;  p += (size_t)3072 * 1024 * 2;
  f16* wpT = (f16*)p;  p += (size_t)1024 * 1024 * 2;
  f16* qkb = (f16*)p;  p += (size_t)4096 * 2048 * 2;        // Q (cols<1024; K-half unused)
  f16* vTb = (f16*)p;  p += (size_t)32 * 256 * 64 * 8 * 2;  // V blocked
  f16* kbb = (f16*)p;  p += (size_t)32 * 131072 * 2;        // K fragment-native (8MB)
  f16* aob = (f16*)p;  p += (size_t)4096 * 1024 * 2;
  if ((size_t)(p - (char*)d_ws) > ws_size) return;

  k_prep<<<8192, 256, 0, stream>>>(x, xh, w_attn, waT, w_proj, wpT);
  k_gemm<0><<<dim3(32, 24), 256, 0, stream>>>(xh, waT, b_attn, qkb, kbb, vTb, nullptr);
  k_attn<<<1024, 256, 0, stream>>>(qkb, kbb, vTb, aob);
  k_gemm<1><<<dim3(32, 8), 256, 0, stream>>>(aob, wpT, b_proj, nullptr, nullptr, nullptr, out);
}

// Round 20
// 111.375 us; speedup vs baseline: 1.1363x; 1.1363x over previous
//
#include <hip/hip_runtime.h>

typedef _Float16 f16;
typedef _Float16 f16x8 __attribute__((ext_vector_type(8)));
typedef _Float16 f16x4 __attribute__((ext_vector_type(4)));
typedef float    f32x4 __attribute__((ext_vector_type(4)));
typedef unsigned int u32;
typedef unsigned int u32x4 __attribute__((ext_vector_type(4)));

#define LOG2E 1.44269504088896340736f
#define EXPC  (13.0f * 1.44269504088896340736f)   // fixed softmax shift (log2 units)

__device__ __forceinline__ void gload_lds16(const void* g, void* l) {
  __builtin_amdgcn_global_load_lds(
      (const __attribute__((address_space(1))) void*)g,
      (__attribute__((address_space(3))) void*)l, 16, 0, 0);
}

__device__ __forceinline__ void block_sync() {
  asm volatile("" ::: "memory");
  __builtin_amdgcn_s_barrier();
  asm volatile("" ::: "memory");
}

// ---------------- fused prep: cast_x (blocks 0..4095) + w_attn^T (4096..7167)
// + w_proj^T (7168..8191), one launch ----------------
__global__ __launch_bounds__(256)
void k_prep(const float* __restrict__ x, f16* __restrict__ xh,
            const float* __restrict__ w_attn, f16* __restrict__ waT,
            const float* __restrict__ w_proj, f16* __restrict__ wpT) {
  __shared__ float tile[32][33];
  const int bid = blockIdx.x;
  const int t = threadIdx.x;
  if (bid < 4096) {
    int i = bid * 256 + t;
    f32x4 v = ((const f32x4*)x)[i];
    f16x4 o;
    o[0] = (f16)v[0]; o[1] = (f16)v[1]; o[2] = (f16)v[2]; o[3] = (f16)v[3];
    ((f16x4*)xh)[i] = o;
    return;
  }
  const float* in; f16* out; int R, C, bx, by;
  if (bid < 4096 + 3072) {
    int q = bid - 4096; in = w_attn; out = waT; R = 1024; C = 3072;
    bx = q % 96; by = q / 96;
  } else {
    int q = bid - 7168; in = w_proj; out = wpT; R = 1024; C = 1024;
    bx = q % 32; by = q / 32;
  }
  int tx = t & 31, ty = t >> 5;   // (32,8)
  int c0 = bx * 32, r0 = by * 32;
#pragma unroll
  for (int i = 0; i < 4; i++)
    tile[ty + i * 8][tx] = in[(size_t)(r0 + ty + i * 8) * C + c0 + tx];
  __syncthreads();
#pragma unroll
  for (int i = 0; i < 4; i++)
    out[(size_t)(c0 + ty + i * 8) * R + r0 + tx] = (f16)tile[tx][ty + i * 8];
}

// ---------------- GEMM: A[M,1024] fp16 @ BT[N,1024] fp16 ----------------
// 2-phase prefetch, double-buffered 64KB LDS, T2 XOR bank-swizzle (R10-proven).
// EPI 0: n<2048 -> qk (Q scaled by LOG2E); n>=2048 -> V blocked vT2 via LDS transpose.
// EPI 1: float out + b_proj.
template <int EPI>
__global__ __launch_bounds__(256)
void k_gemm(const f16* __restrict__ A, const f16* __restrict__ BT,
            const float* __restrict__ bias,
            f16* __restrict__ out_qk, f16* __restrict__ out_vT,
            float* __restrict__ out_f) {
  constexpr int K = 1024;
  __shared__ f16 smem[4][128 * 64];
  const int t = threadIdx.x;
  const int l = t & 63;
  const int w = t >> 6;
  const int wm = (w >> 1) * 64;
  const int wn = (w & 1) * 64;
  const int m0 = blockIdx.x * 128;
  const int n0 = blockIdx.y * 128;
  const int lr = l & 15;
  const int lg = l >> 4;
  const int fr8 = lr & 7;

  const int row8g = t >> 3;
  const int scg = (t & 7) ^ (row8g & 7);
  const f16* Ap = A + (size_t)(m0 + row8g) * K + scg * 8;
  const f16* Bp = BT + (size_t)(n0 + row8g) * K + scg * 8;

#define GSTAGE(buf) do { \
    _Pragma("unroll") \
    for (int i2 = 0; i2 < 4; i2++) \
      gload_lds16(Ap + (size_t)(i2 * 32) * K, &smem[buf][(i2 * 256 + t) * 8]); \
    _Pragma("unroll") \
    for (int i2 = 0; i2 < 4; i2++) \
      gload_lds16(Bp + (size_t)(i2 * 32) * K, &smem[2 + buf][(i2 * 256 + t) * 8]); \
    Ap += 64; Bp += 64; } while (0)

  f32x4 acc[4][4] = {};

#define GCOMPUTE(buf) do { \
    _Pragma("unroll") \
    for (int kk = 0; kk < 64; kk += 32) { \
      const int cbase = (kk >> 3) + lg; \
      f16x8 af[4], bf[4]; \
      _Pragma("unroll") \
      for (int i = 0; i < 4; i++) \
        af[i] = *(const f16x8*)&smem[buf][((wm + i * 16 + lr) * 8 + (cbase ^ fr8)) * 8]; \
      _Pragma("unroll") \
      for (int j = 0; j < 4; j++) \
        bf[j] = *(const f16x8*)&smem[2 + buf][((wn + j * 16 + lr) * 8 + (cbase ^ fr8)) * 8]; \
      _Pragma("unroll") \
      for (int i = 0; i < 4; i++) \
        _Pragma("unroll") \
        for (int j = 0; j < 4; j++) \
          acc[i][j] = __builtin_amdgcn_mfma_f32_16x16x32_f16(af[i], bf[j], acc[i][j], 0, 0, 0); \
    } } while (0)

  GSTAGE(0);
  asm volatile("s_waitcnt vmcnt(0)" ::: "memory");
  block_sync();

  for (int kt = 0; kt < 16; kt += 2) {
    GSTAGE(1);
    GCOMPUTE(0);
    asm volatile("s_waitcnt vmcnt(0)" ::: "memory");
    block_sync();
    if (kt + 2 < 16) GSTAGE(0);
    GCOMPUTE(1);
    asm volatile("s_waitcnt vmcnt(0)" ::: "memory");
    block_sync();
  }
#undef GSTAGE
#undef GCOMPUTE

  if (EPI == 1) {
#pragma unroll
    for (int i = 0; i < 4; i++) {
      int mbase = m0 + wm + i * 16 + (l >> 4) * 4;
#pragma unroll
      for (int j = 0; j < 4; j++) {
        int n = n0 + wn + j * 16 + lr;
        float bv = bias[n];
#pragma unroll
        for (int r = 0; r < 4; r++)
          out_f[(size_t)(mbase + r) * 1024 + n] = acc[i][j][r] + bv;
      }
    }
  } else if (n0 < 2048) {
#pragma unroll
    for (int i = 0; i < 4; i++) {
      int mbase = m0 + wm + i * 16 + (l >> 4) * 4;
#pragma unroll
      for (int j = 0; j < 4; j++) {
        int n = n0 + wn + j * 16 + lr;
        float bv = bias[n];
        float sc = (n0 + wn + j * 16 < 1024) ? LOG2E : 1.0f;
#pragma unroll
        for (int r = 0; r < 4; r++)
          out_qk[(size_t)(mbase + r) * 2048 + n] = (f16)((acc[i][j][r] + bv) * sc);
      }
    }
  } else {
    // V half -> blocked layout vT2[bh][kv/8][d:64][j:8].
    f16* scr = &smem[0][0];
#pragma unroll
    for (int i = 0; i < 4; i++) {
      int s0 = wm + i * 16 + (l >> 4) * 4;
#pragma unroll
      for (int j = 0; j < 4; j++) {
        int nl = wn + j * 16 + lr;
        float bv = bias[n0 + nl];
        f16x4 pv;
#pragma unroll
        for (int r = 0; r < 4; r++) pv[r] = (f16)(acc[i][j][r] + bv);
        *(f16x4*)&scr[nl * 128 + (s0 ^ ((nl & 15) << 3))] = pv;
      }
    }
    block_sync();
    const int b = m0 >> 11;
    const int kvc0 = (m0 & 2047) >> 3;
    const int h0 = (n0 - 2048) >> 6;
    const int l64 = t & 63;
    const int wv = t >> 6;
#pragma unroll
    for (int p = 0; p < 8; p++) {
      int pair = wv + p * 4;
      int kvcl = pair & 15;
      int hgl  = pair >> 4;
      int nl = hgl * 64 + l64;
      f16x8 vv = *(const f16x8*)&scr[nl * 128 + ((kvcl * 8) ^ ((nl & 15) << 3))];
      size_t dst = (((size_t)(b * 16 + h0 + hgl) * 256 + kvc0 + kvcl) * 64 + l64) * 8;
      *(f16x8*)&out_vT[dst] = vv;
    }
  }
}

// ---------------- flash attention: R17 structure (best measured: 58us) ----------------
// grid 1024 (XCD-swizzled), 4-wave blocks, 16 q-rows/wave, KVBLK=64, K-only 16KB
// dbuf LDS (block-shared: the cross-wave bandwidth amplifier — R19's barrier-free
// version oversubscribed L2 at 36 TB/s and regressed), V direct from L2 (blocked
// vT2, 256B-coalesced). Permuted K staging: LDS row rho sources global row
// pi(rho); fragment-read rows ks*32+cc*16+lr, slot xor lr&7 -> all 8 slots,
// conflicts = 0 (R16/R17 verified). Raw v_exp_f32. Swapped mfma(K,Q); Q
// pre-scaled LOG2E; QK C-init -EXPC; ones-MFMA row sums.
__global__ __launch_bounds__(256, 4)
void k_attn(const f16* __restrict__ qk, const f16* __restrict__ vT,
            f16* __restrict__ aout) {
  __shared__ f16 Kl[2][64 * 64];
  const int t = threadIdx.x;
  const int l = t & 63;
  const int w = t >> 6;
  const int lr = l & 15;
  const int lg = l >> 4;
  const int lk = lg * 8;
  const int r7x = lr & 7;

  const int o  = (blockIdx.x & 7) * 128 + (blockIdx.x >> 3);
  const int qt = o & 31;
  const int bh = o >> 5;
  const int b  = bh >> 4;
  const int h  = bh & 15;
  const int q0 = qt * 64 + w * 16;

  const f16* qp = qk + (size_t)(b * 2048 + q0 + lr) * 2048 + h * 64 + lk;
  f16x8 qf0 = *(const f16x8*)qp;
  f16x8 qf1 = *(const f16x8*)(qp + 32);

  const f16* kg = qk + (size_t)(b * 2048) * 2048 + 1024 + h * 64;
  const int r5 = t >> 3;                 // 0..31 (= cc*16 + u)
  const int u_s = r5 & 15;
  const int prow = (u_s >> 2) * 8 + (u_s & 3) * 2 + (r5 >> 4);
  const int sc_s = ((t & 7) ^ (r5 & 7)) << 3;

  const f16* vg0 = vT + (((size_t)bh * 256 + lg) * 64 + lr) * 8;

#define STAGE(B) do { \
    gload_lds16(kg + (size_t)(prow     ) * 2048 + sc_s, &Kl[B][(      t) * 8]); \
    gload_lds16(kg + (size_t)(prow + 32) * 2048 + sc_s, &Kl[B][(256 + t) * 8]); \
    kg += 64 * 2048; } while (0)

  f32x4 oa[4] = {};
  f32x4 ssum = {};
  const f32x4 initc = {-EXPC, -EXPC, -EXPC, -EXPC};
  f16x8 ones;
#pragma unroll
  for (int j = 0; j < 8; j++) ones[j] = (f16)1.0f;

  STAGE(0);
  asm volatile("s_waitcnt vmcnt(0)" ::: "memory");
  block_sync();

#define TILE_BODY(B) do { \
    f16x8 vfr[4][2]; \
    _Pragma("unroll") \
    for (int c4 = 0; c4 < 4; c4++) \
      _Pragma("unroll") \
      for (int ks = 0; ks < 2; ks++) \
        vfr[c4][ks] = *(const f16x8*)(vg0 + ks * 2048 + c4 * 128); \
    f32x4 sa[4]; \
    __builtin_amdgcn_s_setprio(1); \
    _Pragma("unroll") \
    for (int c = 0; c < 4; c++) { \
      const int ks = c >> 1, cc = c & 1; \
      const int row = ks * 32 + cc * 16 + lr; \
      f16x8 kf0 = *(const f16x8*)&Kl[B][(row * 8 + (lg ^ r7x)) * 8]; \
      f16x8 kf1 = *(const f16x8*)&Kl[B][(row * 8 + ((lg + 4) ^ r7x)) * 8]; \
      sa[c] = __builtin_amdgcn_mfma_f32_16x16x32_f16(kf0, qf0, initc, 0, 0, 0); \
      sa[c] = __builtin_amdgcn_mfma_f32_16x16x32_f16(kf1, qf1, sa[c], 0, 0, 0); \
    } \
    __builtin_amdgcn_s_setprio(0); \
    _Pragma("unroll") \
    for (int c = 0; c < 4; c++) \
      _Pragma("unroll") \
      for (int r = 0; r < 4; r++) \
        sa[c][r] = __builtin_amdgcn_exp2f(sa[c][r]); \
    u32 pka[2][4]; \
    _Pragma("unroll") \
    for (int ks = 0; ks < 2; ks++) \
      _Pragma("unroll") \
      for (int u = 0; u < 4; u++) \
        pka[ks][u] = __builtin_bit_cast(u32, \
            __builtin_amdgcn_cvt_pkrtz(sa[2 * ks][u], sa[2 * ks + 1][u])); \
    f16x8 pa0 = __builtin_bit_cast(f16x8, (u32x4){pka[0][0], pka[0][1], pka[0][2], pka[0][3]}); \
    f16x8 pa1 = __builtin_bit_cast(f16x8, (u32x4){pka[1][0], pka[1][1], pka[1][2], pka[1][3]}); \
    __builtin_amdgcn_s_setprio(1); \
    ssum = __builtin_amdgcn_mfma_f32_16x16x32_f16(pa0, ones, ssum, 0, 0, 0); \
    ssum = __builtin_amdgcn_mfma_f32_16x16x32_f16(pa1, ones, ssum, 0, 0, 0); \
    _Pragma("unroll") \
    for (int c4 = 0; c4 < 4; c4++) { \
      oa[c4] = __builtin_amdgcn_mfma_f32_16x16x32_f16(pa0, vfr[c4][0], oa[c4], 0, 0, 0); \
      oa[c4] = __builtin_amdgcn_mfma_f32_16x16x32_f16(pa1, vfr[c4][1], oa[c4], 0, 0, 0); \
    } \
    __builtin_amdgcn_s_setprio(0); \
    vg0 += 4096; \
    asm volatile("s_waitcnt vmcnt(0)" ::: "memory"); \
    block_sync(); } while (0)

  for (int tt = 0; tt < 32; tt += 2) {
    STAGE(1);
    TILE_BODY(0);
    if (tt + 2 < 32) STAGE(0);
    TILE_BODY(1);
  }
#undef STAGE
#undef TILE_BODY

  // ---- final: normalize (ssum[r] = row-sum for q = q0 + lg*4 + r) ----
#pragma unroll
  for (int r = 0; r < 4; r++) {
    float ia = 1.0f / ssum[r];
    size_t rowa = (size_t)(b * 2048 + q0 + lg * 4 + r);
#pragma unroll
    for (int c4 = 0; c4 < 4; c4++)
      aout[rowa * 1024 + h * 64 + c4 * 16 + lr] = (f16)(oa[c4][r] * ia);
  }
}

// ---------------- launch ----------------
extern "C" void kernel_launch(void* const* d_in, const int* in_sizes, int n_in,
                              void* d_out, int out_size, void* d_ws, size_t ws_size,
                              hipStream_t stream) {
  const float* x      = (const float*)d_in[0];
  const float* w_attn = (const float*)d_in[1];
  const float* b_attn = (const float*)d_in[2];
  const float* w_proj = (const float*)d_in[3];
  const float* b_proj = (const float*)d_in[4];
  float* out = (float*)d_out;

  char* p = (char*)d_ws;
  f16* xh  = (f16*)p;  p += (size_t)4096 * 1024 * 2;
  f16* waT = (f16*)p;  p += (size_t)3072 * 1024 * 2;
  f16* wpT = (f16*)p;  p += (size_t)1024 * 1024 * 2;
  f16* qkb = (f16*)p;  p += (size_t)4096 * 2048 * 2;   // Q|K (Q pre-scaled by LOG2E)
  f16* vTb = (f16*)p;  p += (size_t)32 * 256 * 64 * 8 * 2;  // V blocked [bh][kv/8][64][8]
  f16* aob = (f16*)p;  p += (size_t)4096 * 1024 * 2;
  if ((size_t)(p - (char*)d_ws) > ws_size) return;

  k_prep<<<8192, 256, 0, stream>>>(x, xh, w_attn, waT, w_proj, wpT);
  k_gemm<0><<<dim3(32, 24), 256, 0, stream>>>(xh, waT, b_attn, qkb, vTb, nullptr);
  k_attn<<<1024, 256, 0, stream>>>(qkb, vTb, aob);
  k_gemm<1><<<dim3(32, 8), 256, 0, stream>>>(aob, wpT, b_proj, nullptr, nullptr, out);
}